// Round 12
// baseline (300.226 us; speedup 1.0000x reference)
//
#include <hip/hip_runtime.h>
#include <cmath>

typedef short short8 __attribute__((ext_vector_type(8)));
typedef unsigned short u16x8 __attribute__((ext_vector_type(8)));
typedef float f32x4 __attribute__((ext_vector_type(4)));

struct EncParams { float scale[10]; int res[10]; };

__device__ __forceinline__ unsigned short f2bf(float f) {
  unsigned u = __builtin_bit_cast(unsigned, f);
  return (unsigned short)((u + 0x7FFFu + ((u >> 16) & 1u)) >> 16);  // RNE
}

// ---------------- batched hashgrid encode: NL levels, all gathers issued
// before any FMA (3x the outstanding-miss depth of the serial version).
// Arithmetic per level is IDENTICAL to the R5/R9/R11 enc_level.
template<int NL>
__device__ __forceinline__ void enc_levels(const float* __restrict__ table,
    float x, float y, const float* sc, const int* rs, const int* lid,
    unsigned short* er) {
  unsigned idx[NL][4];
  float w[NL][4];
#pragma unroll
  for (int t = 0; t < NL; ++t) {
    float posx = __fadd_rn(__fmul_rn(x, sc[t]), 0.5f);
    float posy = __fadd_rn(__fmul_rn(y, sc[t]), 0.5f);
    float gx = floorf(posx), gy = floorf(posy);
    float fx = posx - gx, fy = posy - gy;
    unsigned px = (unsigned)gx, py = (unsigned)gy;
    int res = rs[t];
    if (res * res <= (1 << 20)) {    // dense: row-major x + y*res
      unsigned b = px + py * (unsigned)res;
      idx[t][0] = b; idx[t][1] = b + 1u;
      idx[t][2] = b + (unsigned)res; idx[t][3] = b + (unsigned)res + 1u;
    } else {                         // spatial hash (level 9 only)
      unsigned hy0 = py * 2654435761u;
      unsigned hy1 = hy0 + 2654435761u;
      idx[t][0] = (px ^ hy0) & 0xFFFFFu;
      idx[t][1] = ((px + 1u) ^ hy0) & 0xFFFFFu;
      idx[t][2] = (px ^ hy1) & 0xFFFFFu;
      idx[t][3] = ((px + 1u) ^ hy1) & 0xFFFFFu;
    }
    float omx = 1.0f - fx, omy = 1.0f - fy;
    w[t][0] = omx * omy; w[t][1] = fx * omy;
    w[t][2] = omx * fy;  w[t][3] = fx * fy;
  }
  float4 v[NL][4][2];                // issue ALL gathers up front
#pragma unroll
  for (int t = 0; t < NL; ++t) {
    const float4* tl = reinterpret_cast<const float4*>(table) + ((size_t)lid[t] << 21);
#pragma unroll
    for (int c = 0; c < 4; ++c) {
      v[t][c][0] = tl[2 * (size_t)idx[t][c]];
      v[t][c][1] = tl[2 * (size_t)idx[t][c] + 1];
    }
  }
#pragma unroll
  for (int t = 0; t < NL; ++t) {
    float acc[8] = {0.f,0.f,0.f,0.f,0.f,0.f,0.f,0.f};
#pragma unroll
    for (int c = 0; c < 4; ++c) {
      float wc = w[t][c];
      acc[0] = fmaf(wc, v[t][c][0].x, acc[0]); acc[1] = fmaf(wc, v[t][c][0].y, acc[1]);
      acc[2] = fmaf(wc, v[t][c][0].z, acc[2]); acc[3] = fmaf(wc, v[t][c][0].w, acc[3]);
      acc[4] = fmaf(wc, v[t][c][1].x, acc[4]); acc[5] = fmaf(wc, v[t][c][1].y, acc[5]);
      acc[6] = fmaf(wc, v[t][c][1].z, acc[6]); acc[7] = fmaf(wc, v[t][c][1].w, acc[7]);
    }
    u16x8 o;
#pragma unroll
    for (int j = 0; j < 8; ++j) o[j] = f2bf(acc[j]);
    *reinterpret_cast<u16x8*>(er + 8 * lid[t]) = o;
  }
}

// ---------------- fused encode + MLP (R11 dataflow + scheduling only) ----------------
// FROZEN: mfma operand order (act arg0, W arg1), scalar epilogues, no d_ws,
// separate encS/hS, BM=128/512thr. NEW (schedule-only, bit-identical math):
// batched encode gathers; W1 fragments built before the barrier; W2 f32
// prefetched one ks-iteration ahead of the MFMAs consuming it.
__global__ __launch_bounds__(512, 2) void nf_main(
    const float* __restrict__ coords, const float* __restrict__ table,
    const float* __restrict__ w1, const float* __restrict__ w2,
    const float* __restrict__ b1v, const float* __restrict__ b2v,
    float* __restrict__ out, EncParams P) {
  __shared__ __align__(16) unsigned short encS[128][104];  // 26,624 B
  __shared__ __align__(16) unsigned short hS[128][392];    // 100,352 B
  const int tid = threadIdx.x;
  const size_t rowBase = (size_t)blockIdx.x * 128;
  const int lane = tid & 63, wv = tid >> 6;      // 8 waves
  const int lr = lane & 15, lhi = lane >> 4;

  // ---- encode phase: 4 threads per point, disjoint level sets ----
  {
    const int p = tid & 127, g = tid >> 7;
    float2 c = reinterpret_cast<const float2*>(coords)[rowBase + p];
    unsigned short* er = &encS[p][0];
    if (g == 0) {
      const int L[3] = {0, 4, 8};
      const float sc[3] = {P.scale[0], P.scale[4], P.scale[8]};
      const int rs[3] = {P.res[0], P.res[4], P.res[8]};
      enc_levels<3>(table, c.x, c.y, sc, rs, L, er);
    } else if (g == 1) {
      const int L[3] = {1, 5, 9};
      const float sc[3] = {P.scale[1], P.scale[5], P.scale[9]};
      const int rs[3] = {P.res[1], P.res[5], P.res[9]};
      enc_levels<3>(table, c.x, c.y, sc, rs, L, er);
    } else if (g == 2) {
      const int L[2] = {2, 6};
      const float sc[2] = {P.scale[2], P.scale[6]};
      const int rs[2] = {P.res[2], P.res[6]};
      enc_levels<2>(table, c.x, c.y, sc, rs, L, er);
      u16x8 z = {};
      *reinterpret_cast<u16x8*>(er + 80) = z;   // zero pad k=80..87
    } else {
      const int L[2] = {3, 7};
      const float sc[2] = {P.scale[3], P.scale[7]};
      const int rs[2] = {P.res[3], P.res[7]};
      enc_levels<2>(table, c.x, c.y, sc, rs, L, er);
      u16x8 z = {};
      *reinterpret_cast<u16x8*>(er + 88) = z;   // zero pad k=88..95
    }
  }

  // ---- W1 fragments: independent of encode; build before the barrier so the
  // loads overlap the encode gathers still in flight. 36 VGPR live across it.
  short8 bW1[3][3];
#pragma unroll
  for (int ks = 0; ks < 3; ++ks)
#pragma unroll
    for (int cf = 0; cf < 3; ++cf) {
      const int colB = 48 * wv + 16 * cf + lr;
#pragma unroll
      for (int j = 0; j < 8; ++j) {
        int k = 32 * ks + 8 * lhi + j;
        bW1[ks][cf][j] = (k < 80) ? (short)f2bf(w1[(size_t)k * 384 + colB]) : (short)0;
      }
    }
  __syncthreads();

  // ---- layer 1: [128x96] x [96 x (48 per wave)] ----
  f32x4 acc1[8][3];
#pragma unroll
  for (int ri = 0; ri < 8; ++ri)
#pragma unroll
    for (int cf = 0; cf < 3; ++cf) acc1[ri][cf] = (f32x4){0.f, 0.f, 0.f, 0.f};
#pragma unroll
  for (int ks = 0; ks < 3; ++ks) {
    short8 a[8];
#pragma unroll
    for (int ri = 0; ri < 8; ++ri)
      a[ri] = *reinterpret_cast<const short8*>(&encS[16 * ri + lr][32 * ks + 8 * lhi]);
#pragma unroll
    for (int cf = 0; cf < 3; ++cf)
#pragma unroll
      for (int ri = 0; ri < 8; ++ri)
        acc1[ri][cf] = __builtin_amdgcn_mfma_f32_16x16x32_bf16(a[ri], bW1[ks][cf], acc1[ri][cf], 0, 0, 0);
  }
#pragma unroll
  for (int ri = 0; ri < 8; ++ri)
#pragma unroll
    for (int cf = 0; cf < 3; ++cf) {
      int col = 48 * wv + 16 * cf + lr;
      float bb = b1v[col];
#pragma unroll
      for (int j = 0; j < 4; ++j) {
        int r = 16 * ri + 4 * lhi + j;
        float v = acc1[ri][cf][j] + bb;
        hS[r][col] = f2bf(fmaxf(v, 0.0f));
      }
    }
  __syncthreads();

  // ---- layer 2: [128x384] x [384 x (96 per wave)], W2 prefetched 1 ks ahead ----
#pragma unroll
  for (int cc = 0; cc < 2; ++cc) {
    f32x4 acc[8][3];
#pragma unroll
    for (int ri = 0; ri < 8; ++ri)
#pragma unroll
      for (int cf = 0; cf < 3; ++cf) acc[ri][cf] = (f32x4){0.f, 0.f, 0.f, 0.f};

    float wnxt[3][8];                          // f32 staging for ks-iteration
#pragma unroll
    for (int cf = 0; cf < 3; ++cf) {
      const int colB = 96 * wv + 48 * cc + 16 * cf + lr;
#pragma unroll
      for (int j = 0; j < 8; ++j)
        wnxt[cf][j] = w2[(size_t)(8 * lhi + j) * 768 + colB];   // ks=0
    }
#pragma unroll
    for (int ks = 0; ks < 12; ++ks) {
      short8 a[8];
#pragma unroll
      for (int ri = 0; ri < 8; ++ri)
        a[ri] = *reinterpret_cast<const short8*>(&hS[16 * ri + lr][32 * ks + 8 * lhi]);
      short8 b[3];
#pragma unroll
      for (int cf = 0; cf < 3; ++cf)
#pragma unroll
        for (int j = 0; j < 8; ++j)
          b[cf][j] = (short)f2bf(wnxt[cf][j]);   // cvt current ks
      if (ks < 11) {                             // prefetch ks+1 (compile-time)
#pragma unroll
        for (int cf = 0; cf < 3; ++cf) {
          const int colB = 96 * wv + 48 * cc + 16 * cf + lr;
#pragma unroll
          for (int j = 0; j < 8; ++j)
            wnxt[cf][j] = w2[(size_t)(32 * (ks + 1) + 8 * lhi + j) * 768 + colB];
        }
      }
#pragma unroll
      for (int cf = 0; cf < 3; ++cf)
#pragma unroll
        for (int ri = 0; ri < 8; ++ri)
          acc[ri][cf] = __builtin_amdgcn_mfma_f32_16x16x32_bf16(a[ri], b[cf], acc[ri][cf], 0, 0, 0);
    }
#pragma unroll
    for (int ri = 0; ri < 8; ++ri)
#pragma unroll
      for (int cf = 0; cf < 3; ++cf) {
        int col = 96 * wv + 48 * cc + 16 * cf + lr;
        float bb = b2v[col];
#pragma unroll
        for (int j = 0; j < 4; ++j) {
          int r = 16 * ri + 4 * lhi + j;
          out[(rowBase + r) * 768 + col] = acc[ri][cf][j] + bb;
        }
      }
  }
}

extern "C" void kernel_launch(void* const* d_in, const int* in_sizes, int n_in,
                              void* d_out, int out_size, void* d_ws, size_t ws_size,
                              hipStream_t stream) {
  const float* coords = (const float*)d_in[0];
  const float* table  = (const float*)d_in[1];
  const float* w1     = (const float*)d_in[2];
  const float* b1     = (const float*)d_in[3];
  const float* w2     = (const float*)d_in[4];
  const float* b2     = (const float*)d_in[5];
  float* out = (float*)d_out;

  EncParams P;
  double pls = exp((log(1024.0) - log(16.0)) / 9.0);
  static const int RES[10] = {16, 26, 41, 65, 102, 162, 257, 407, 646, 1025};
  for (int l = 0; l < 10; ++l) {
    double sc = 16.0 * pow(pls, (double)l) - 1.0;
    P.scale[l] = (float)sc;
    P.res[l] = RES[l];
  }

  // FROZEN FAMILY (no d_ws, no operand swap, no LDS union). This round is
  // schedule-only vs the passing R11: batched encode gathers, W1 hoist,
  // W2 ks+1 prefetch — arithmetic and addresses bit-identical.
  nf_main<<<1024, 512, 0, stream>>>(coords, table, w1, w2, b1, b2, out, P);
}